// Round 11
// baseline (62.389 us; speedup 1.0000x reference)
//
#include <hip/hip_runtime.h>

// SE(2) depthwise group conv via bf16 MFMA (fp32 accum), Delta-packed.
// out[b,c,t,y,x] = sum_{o,dy,dx} W[c,t,o,dy,dx] * x[b,c,o,y+dy-2,x+dx-2]
// GEMM per (b,c): D[m=16 pix][n=(t,Dlt)] with Dlt in {0,1} packing TWO output
// rows per MFMA: K = 32 "row-taps" tr=(dyr in 0..5, dx in 0..4) x 8 o = 256,
// B[(dyr,dx,o)][(t,Dlt)] = w[t][dyr-Dlt, dx] (0 if out of range; tr>=30 pad).
// Exact: dyr = dy + Dlt reindexes the row sum. All 16 N-cols useful ->
// MFMA count & LDS-read traffic halved vs the 8-t-in-16 scheme.
// mfma_f32_16x16x32_bf16: A lane l: row=l&15 (pixel), tap tr=cc*4+(l>>4), o=j.
//   D lane l: col=l&15=(t + 8*Dlt), row=(l>>4)*4+reg = pixel -> float4 store.
// LDS x-tile [36 r][36 c][8 o] bf16 = 20.7 KB -> 7 blocks/CU. 32x32 tile.
// Weights: wtab2[c][n16][tr][o] bf16 (256 KB) built once into d_ws.

typedef short bf16x8 __attribute__((ext_vector_type(8)));
typedef float f32x4 __attribute__((ext_vector_type(4)));

__device__ inline unsigned short f2bf(float f) {   // RNE f32->bf16
    unsigned int u = __float_as_uint(f);
    u += 0x7fffu + ((u >> 16) & 1u);
    return (unsigned short)(u >> 16);
}
__device__ inline unsigned pk2(float a, float b) {
    return (unsigned)f2bf(a) | ((unsigned)f2bf(b) << 16);
}

// cos/sin of 2*pi*t/8, f32. NN-rounding margins >=0.035 -> table-vs-libm safe.
__device__ __constant__ float CA8[8] = {1.0f, 0.70710678f, 0.0f, -0.70710678f,
                                        -1.0f, -0.70710678f, 0.0f, 0.70710678f};
__device__ __constant__ float SA8[8] = {0.0f, 0.70710678f, 1.0f, 0.70710678f,
                                        0.0f, -0.70710678f, -1.0f, -0.70710678f};

__device__ inline float rot_w(const float* __restrict__ kern, int c, int t,
                              int o, int dy, int dx) {
    float ca = CA8[t], sa = SA8[t];
    float xx = (float)dx - 2.0f, yy = (float)dy - 2.0f;
    int iy = (int)rintf(sa * xx + ca * yy + 2.0f);  // RNE == jnp.round
    int ix = (int)rintf(ca * xx - sa * yy + 2.0f);
    if (iy >= 0 && iy < 5 && ix >= 0 && ix < 5) {
        int tp = (o - t) & 7;
        return kern[(c * 8 + tp) * 25 + iy * 5 + ix];
    }
    return 0.0f;
}

// wtab2[((c*16 + n16)*32 + tr)*8 + o], n16 = t + 8*Dlt; 131072 bf16 = 256 KB
__global__ __launch_bounds__(256)
void build_w2(const float* __restrict__ kern, unsigned short* __restrict__ wtab) {
    int e = blockIdx.x * 256 + threadIdx.x;
    if (e >= 131072) return;
    int o   = e & 7;
    int tr  = (e >> 3) & 31;
    int n16 = (e >> 8) & 15;
    int c   = e >> 12;
    int t   = n16 & 7, dlt = n16 >> 3;
    float w = 0.0f;
    if (tr < 30) {
        int dyr = tr / 5, dx = tr - 5 * dyr;
        int dy  = dyr - dlt;
        if (dy >= 0 && dy < 5) w = rot_w(kern, c, t, o, dy, dx);
    }
    wtab[e] = f2bf(w);
}

template <bool TAB>
__global__ __launch_bounds__(256)
void se2_mfma(const float* __restrict__ x, const float* __restrict__ kern,
              const unsigned short* __restrict__ wtab, float* __restrict__ out) {
    __shared__ __align__(16) unsigned short ldsx[36 * 36 * 8];  // 20736 B

    // XCD-chunked bijective swizzle: 4096 blocks, 8 XCDs, 512 per XCD.
    const int bid = (blockIdx.x & 7) * 512 + (blockIdx.x >> 3);
    const int tx = bid & 3, ty = (bid >> 2) & 3;
    const int bc = bid >> 4;          // b*32 + c
    const int c  = bc & 31;
    const int X0 = tx * 32, Y0 = ty * 32;
    const int tid = threadIdx.x;

    const int lane = tid & 63;
    const int wv   = tid >> 6;        // wave: rows [wv*8, wv*8+8)
    const int g    = lane >> 4;       // k-group (4 taps each)
    const int m16  = lane & 15;       // A-row pixel / D-col n16

    const float* xbase = x + (size_t)bc * 131072;

    auto loadch = [&](int e, float (&v)[8]) {
        int r = e / 36, col = e - r * 36;
        int gy = Y0 - 2 + r, gx = X0 - 2 + col;
        if (gy >= 0 && gy < 128 && gx >= 0 && gx < 128) {
            const float* src = xbase + gy * 128 + gx;
#pragma unroll
            for (int o = 0; o < 8; ++o) v[o] = src[o * 16384];
        } else {
#pragma unroll
            for (int o = 0; o < 8; ++o) v[o] = 0.0f;
        }
    };
    auto packch = [&](int e, const float (&v)[8]) {
        *reinterpret_cast<uint4*>(&ldsx[e * 8]) =
            make_uint4(pk2(v[0], v[1]), pk2(v[2], v[3]),
                       pk2(v[4], v[5]), pk2(v[6], v[7]));
    };

    float sA[8], sB[8];
    loadch(tid, sA);          // staging loads issued first (critical path)
    loadch(tid + 256, sB);

    bf16x8 wfrag[8];
    int    tapoff[8];
#pragma unroll
    for (int cc = 0; cc < 8; ++cc) {
        int tr  = cc * 4 + g;
        int trc = tr < 30 ? tr : 29;              // A addr clamp (B is zero there)
        int dyr = trc / 5, dx = trc - 5 * dyr;
        tapoff[cc] = (dyr * 36 + dx) * 8;         // in shorts
        if constexpr (TAB)
            wfrag[cc] = *reinterpret_cast<const bf16x8*>(
                &wtab[((c * 16 + m16) * 32 + tr) * 8]);
    }

    if constexpr (!TAB) {
        // fallback: build this block's [16 n][32 tr][8 o] table in LDS
        __shared__ __align__(16) unsigned short ldsw[16 * 32 * 8];  // 8 KB
        for (int e = tid; e < 4096; e += 256) {
            int o = e & 7, tr = (e >> 3) & 31, n16 = e >> 8;
            int t = n16 & 7, dlt = n16 >> 3;
            float w = 0.0f;
            if (tr < 30) {
                int dyr = tr / 5, dx = tr - 5 * dyr;
                int dy  = dyr - dlt;
                if (dy >= 0 && dy < 5) w = rot_w(kern, c, t, o, dy, dx);
            }
            ldsw[e] = f2bf(w);
        }
        __syncthreads();
#pragma unroll
        for (int cc = 0; cc < 8; ++cc)
            wfrag[cc] = *reinterpret_cast<const bf16x8*>(
                &ldsw[(m16 * 32 + cc * 4 + g) * 8]);
    }

    packch(tid, sA);
    packch(tid + 256, sB);
    loadch(tid + 512, sA);
    loadch(tid + 768, sB);
    packch(tid + 512, sA);
    packch(tid + 768, sB);
    loadch(tid + 1024, sA);
    if (tid < 16) loadch(tid + 1280, sB);
    packch(tid + 1024, sA);
    if (tid < 16) packch(tid + 1280, sB);
    __syncthreads();

    // D decode: n16 = t + 8*Dlt; lane writes pixels g*4..g*4+3 as float4
    const int t_o = m16 & 7, dlt = m16 >> 3;
    float* outl = out + (size_t)bc * 131072 + (size_t)t_o * 16384 +
                  (size_t)(Y0 + dlt) * 128 + X0 + g * 4;

    // ---- compute: 4 row-pairs x 2 xh per wave, unroll 2 -> dual chains ----
#pragma unroll 2
    for (int s = 0; s < 8; ++s) {
        int pr = s >> 1;                  // row-pair 0..3
        int xh = s & 1;
        int yl = wv * 8 + pr * 2;         // base output row (Dlt adds 0/1)
        int baseS = (yl * 36 + xh * 16 + m16) * 8;
        f32x4 acc = {0.f, 0.f, 0.f, 0.f};
#pragma unroll
        for (int cc = 0; cc < 8; ++cc) {
            bf16x8 xf = *reinterpret_cast<const bf16x8*>(&ldsx[baseS + tapoff[cc]]);
            acc = __builtin_amdgcn_mfma_f32_16x16x32_bf16(xf, wfrag[cc], acc, 0, 0, 0);
        }
        *reinterpret_cast<float4*>(outl + (size_t)yl * 128 + xh * 16) =
            make_float4(acc[0], acc[1], acc[2], acc[3]);
    }
}

extern "C" void kernel_launch(void* const* d_in, const int* in_sizes, int n_in,
                              void* d_out, int out_size, void* d_ws, size_t ws_size,
                              hipStream_t stream) {
    const float* x    = (const float*)d_in[0];
    const float* kern = (const float*)d_in[1];
    float* out = (float*)d_out;
    dim3 block(256);
    if (ws_size >= 131072 * sizeof(unsigned short)) {
        unsigned short* wtab = (unsigned short*)d_ws;
        build_w2<<<dim3(512), block, 0, stream>>>(kern, wtab);
        se2_mfma<true><<<dim3(4096), block, 0, stream>>>(x, kern, wtab, out);
    } else {
        se2_mfma<false><<<dim3(4096), block, 0, stream>>>(x, kern, nullptr, out);
    }
}

// Round 12
// 56.244 us; speedup vs baseline: 1.1093x; 1.1093x over previous
//
#include <hip/hip_runtime.h>

// SE(2) depthwise group conv via bf16 MFMA (fp32 accum), Delta-packed,
// with LDS-transpose epilogue for coalesced 256B-segment output stores.
//
// out[b,c,t,y,x] = sum_{o,dy,dx} W[c,t,o,dy,dx] * x[b,c,o,y+dy-2,x+dx-2]
// GEMM per (b,c): D[m=16 pix][n=(t,Dlt)], Dlt in {0,1} packs TWO output rows
// per MFMA. K = 32 row-taps tr=(dyr 0..5, dx 0..4) x 8 o = 256:
// B[(dyr,dx,o)][(t,Dlt)] = w[t][dyr-Dlt, dx] (0 OOR; tr>=30 pad).
// mfma_f32_16x16x32_bf16: A lane: row=l&15 (pixel x-offset), tap tr=cc*4+g.
//   D lane l: col=l&15=(t+8*Dlt), row=(l>>4)*4+reg = pixel -> f32x4.
// Block = 16 rows x 64 cols of one (b,c); 4 waves; per wave 8 s-iters
// (2 row-pairs x 4 x-quads) x 8 cc = 64 MFMA. Grid 4096, XCD-chunked.
// LDS union (34944 B -> 4 blocks/CU):
//   stage: [20 r][68 c][8 o] bf16 = 21760 B  (during compute)
//   epil : f32 [8 t][16 y pitch 68] t-stride 1092 (after compute)
// Epilogue store: lane=(yloc,xq): 4 rows x 256B contiguous per instr.

typedef short bf16x8 __attribute__((ext_vector_type(8)));
typedef float f32x4 __attribute__((ext_vector_type(4)));

#define EPIL_TS 1092   // floats per t-plane (16*68 + 4; mod32=4, mod4=0)
#define EPIL_RP 68     // row pitch in floats

__device__ inline unsigned short f2bf(float f) {   // RNE f32->bf16
    unsigned int u = __float_as_uint(f);
    u += 0x7fffu + ((u >> 16) & 1u);
    return (unsigned short)(u >> 16);
}
__device__ inline unsigned pk2(float a, float b) {
    return (unsigned)f2bf(a) | ((unsigned)f2bf(b) << 16);
}

// cos/sin of 2*pi*t/8, f32. NN-rounding margins >=0.035 -> table-vs-libm safe.
__device__ __constant__ float CA8[8] = {1.0f, 0.70710678f, 0.0f, -0.70710678f,
                                        -1.0f, -0.70710678f, 0.0f, 0.70710678f};
__device__ __constant__ float SA8[8] = {0.0f, 0.70710678f, 1.0f, 0.70710678f,
                                        0.0f, -0.70710678f, -1.0f, -0.70710678f};

__device__ inline float rot_w(const float* __restrict__ kern, int c, int t,
                              int o, int dy, int dx) {
    float ca = CA8[t], sa = SA8[t];
    float xx = (float)dx - 2.0f, yy = (float)dy - 2.0f;
    int iy = (int)rintf(sa * xx + ca * yy + 2.0f);  // RNE == jnp.round
    int ix = (int)rintf(ca * xx - sa * yy + 2.0f);
    if (iy >= 0 && iy < 5 && ix >= 0 && ix < 5) {
        int tp = (o - t) & 7;
        return kern[(c * 8 + tp) * 25 + iy * 5 + ix];
    }
    return 0.0f;
}

// wtab2[((c*16 + n16)*32 + tr)*8 + o], n16 = t + 8*Dlt; 131072 bf16 = 256 KB
__global__ __launch_bounds__(256)
void build_w2(const float* __restrict__ kern, unsigned short* __restrict__ wtab) {
    int e = blockIdx.x * 256 + threadIdx.x;
    if (e >= 131072) return;
    int o   = e & 7;
    int tr  = (e >> 3) & 31;
    int n16 = (e >> 8) & 15;
    int c   = e >> 12;
    int t   = n16 & 7, dlt = n16 >> 3;
    float w = 0.0f;
    if (tr < 30) {
        int dyr = tr / 5, dx = tr - 5 * dyr;
        int dy  = dyr - dlt;
        if (dy >= 0 && dy < 5) w = rot_w(kern, c, t, o, dy, dx);
    }
    wtab[e] = f2bf(w);
}

template <bool TAB>
__global__ __launch_bounds__(256)
void se2_mfma(const float* __restrict__ x, const float* __restrict__ kern,
              const unsigned short* __restrict__ wtab, float* __restrict__ out) {
    // union: stage (21760 B, shorts) / epil (34944 B, f32) / fallback ldsw
    __shared__ __align__(16) float ldsbuf[8 * EPIL_TS];   // 34944 B
    unsigned short* stage = reinterpret_cast<unsigned short*>(ldsbuf);
    float* epil = ldsbuf;

    // XCD-chunked bijective swizzle: 4096 blocks, 8 XCDs, 512 per XCD.
    const int bid = (blockIdx.x & 7) * 512 + (blockIdx.x >> 3);
    const int xh2 = bid & 1;           // x half: cols 0-63 / 64-127
    const int ys  = (bid >> 1) & 7;    // 8 row-strips of 16
    const int bc  = bid >> 4;          // b*32 + c
    const int c   = bc & 31;
    const int X0  = xh2 * 64, Y0 = ys * 16;
    const int tid = threadIdx.x;

    const int lane = tid & 63;
    const int wv   = tid >> 6;         // wave: rows [wv*4, wv*4+4)
    const int g    = lane >> 4;        // k-group (4 row-taps)
    const int m16  = lane & 15;        // A-row pixel / D-col n16

    const float* xbase = x + (size_t)bc * 131072;

    // stage chunk e -> (r = e/68, col = e%68); 1360 chunks total
    auto loadch = [&](int e, float (&v)[8]) {
        int r = e / 68, col = e - r * 68;
        int gy = Y0 - 2 + r, gx = X0 - 2 + col;
        if (gy >= 0 && gy < 128 && gx >= 0 && gx < 128) {
            const float* src = xbase + gy * 128 + gx;
#pragma unroll
            for (int o = 0; o < 8; ++o) v[o] = src[o * 16384];
        } else {
#pragma unroll
            for (int o = 0; o < 8; ++o) v[o] = 0.0f;
        }
    };
    auto packch = [&](int e, const float (&v)[8]) {
        *reinterpret_cast<uint4*>(&stage[e * 8]) =
            make_uint4(pk2(v[0], v[1]), pk2(v[2], v[3]),
                       pk2(v[4], v[5]), pk2(v[6], v[7]));
    };

    float sA[8], sB[8];
    loadch(tid, sA);           // staging loads issued first (critical path)
    loadch(tid + 256, sB);

    bf16x8 wfrag[8];
    int    tapoff[8];
#pragma unroll
    for (int cc = 0; cc < 8; ++cc) {
        int tr  = cc * 4 + g;
        int trc = tr < 30 ? tr : 29;   // A addr clamp (B weight is zero there)
        int dyr = trc / 5, dx = trc - 5 * dyr;
        tapoff[cc] = (dyr * 68 + dx) * 8;          // in shorts
        if constexpr (TAB)
            wfrag[cc] = *reinterpret_cast<const bf16x8*>(
                &wtab[((c * 16 + m16) * 32 + tr) * 8]);
    }

    if constexpr (!TAB) {
        // fallback: build [16 n][32 tr][8 o] table in LDS beyond stage region
        unsigned short* ldsw = stage + 12288;      // bytes 24576..32768
        for (int e = tid; e < 4096; e += 256) {
            int o = e & 7, tr = (e >> 3) & 31, n16 = e >> 8;
            int t = n16 & 7, dlt = n16 >> 3;
            float w = 0.0f;
            if (tr < 30) {
                int dyr = tr / 5, dx = tr - 5 * dyr;
                int dy  = dyr - dlt;
                if (dy >= 0 && dy < 5) w = rot_w(kern, c, t, o, dy, dx);
            }
            ldsw[e] = f2bf(w);
        }
        __syncthreads();
#pragma unroll
        for (int cc = 0; cc < 8; ++cc)
            wfrag[cc] = *reinterpret_cast<const bf16x8*>(
                &ldsw[(m16 * 32 + cc * 4 + g) * 8]);
    }

    packch(tid, sA);
    packch(tid + 256, sB);
    loadch(tid + 512, sA);
    loadch(tid + 768, sB);
    packch(tid + 512, sA);
    packch(tid + 768, sB);
    loadch(tid + 1024, sA);
    if (tid < 80) loadch(tid + 1280, sB);
    packch(tid + 1024, sA);
    if (tid < 80) packch(tid + 1280, sB);
    __syncthreads();

    // ---- compute: 8 s-iters (pr = s>>2 row-pair, xq = s&3), all unrolled ----
    f32x4 acc[8];
#pragma unroll
    for (int s = 0; s < 8; ++s) {
        acc[s] = (f32x4){0.f, 0.f, 0.f, 0.f};
        const int yl = wv * 4 + (s >> 2) * 2;
        const int baseS = (yl * 68 + (s & 3) * 16 + m16) * 8;
#pragma unroll
        for (int cc = 0; cc < 8; ++cc) {
            bf16x8 xf = *reinterpret_cast<const bf16x8*>(&stage[baseS + tapoff[cc]]);
            acc[s] = __builtin_amdgcn_mfma_f32_16x16x32_bf16(xf, wfrag[cc], acc[s], 0, 0, 0);
        }
    }
    __syncthreads();   // all waves done reading stage; epil may overwrite

    // ---- epilogue: acc -> LDS f32 [t][y][x] (pitch 68, t-stride 1092) ----
    const int t_o = m16 & 7, dlt = m16 >> 3;
#pragma unroll
    for (int s = 0; s < 8; ++s) {
        int y = wv * 4 + (s >> 2) * 2 + dlt;
        int xx = (s & 3) * 16 + g * 4;
        *reinterpret_cast<f32x4*>(&epil[t_o * EPIL_TS + y * EPIL_RP + xx]) = acc[s];
    }
    __syncthreads();

    // ---- coalesced stores: lane=(yloc,xq); 4 rows x 256B per instr ----
    const int xq   = lane & 15;
    const int yloc = lane >> 4;
    float* outb = out + (size_t)bc * 131072;
#pragma unroll
    for (int j = 0; j < 8; ++j) {
        int t = wv * 2 + (j & 1);
        int y = (j >> 1) * 4 + yloc;
        f32x4 v = *reinterpret_cast<const f32x4*>(
            &epil[t * EPIL_TS + y * EPIL_RP + xq * 4]);
        *reinterpret_cast<f32x4*>(
            outb + (size_t)t * 16384 + (size_t)(Y0 + y) * 128 + X0 + xq * 4) =
            v;
    }
}

extern "C" void kernel_launch(void* const* d_in, const int* in_sizes, int n_in,
                              void* d_out, int out_size, void* d_ws, size_t ws_size,
                              hipStream_t stream) {
    const float* x    = (const float*)d_in[0];
    const float* kern = (const float*)d_in[1];
    float* out = (float*)d_out;
    dim3 block(256);
    if (ws_size >= 131072 * sizeof(unsigned short)) {
        unsigned short* wtab = (unsigned short*)d_ws;
        build_w2<<<dim3(512), block, 0, stream>>>(kern, wtab);
        se2_mfma<true><<<dim3(4096), block, 0, stream>>>(x, kern, wtab, out);
    } else {
        se2_mfma<false><<<dim3(4096), block, 0, stream>>>(x, kern, nullptr, out);
    }
}